// Round 5
// baseline (2129.206 us; speedup 1.0000x reference)
//
#include <hip/hip_runtime.h>

#define T_STEPS 20
#define KK      20
#define NW      50000

typedef __attribute__((ext_vector_type(8))) short bfx8;
typedef __attribute__((ext_vector_type(4))) short sx4;
typedef __attribute__((ext_vector_type(4))) float fx4;
typedef __attribute__((ext_vector_type(2))) float fx2;
typedef __attribute__((ext_vector_type(4))) int   ix4;
typedef __attribute__((ext_vector_type(2))) int   ix2;

__device__ __forceinline__ unsigned f2bfu(float f){
  unsigned u = __builtin_bit_cast(unsigned, f);
  return ((u + 0x7FFFu + ((u >> 16) & 1u)) >> 16);
}
__device__ __forceinline__ unsigned cvtpk(float lo, float hi){
  unsigned r; asm("v_cvt_pk_bf16_f32 %0, %1, %2" : "=v"(r) : "v"(lo), "v"(hi)); return r;
}
__device__ __forceinline__ float hsig(float x){
  return __builtin_amdgcn_fmed3f(fmaf(x, 0.16666667f, 0.5f), 0.f, 1.f);
}
__device__ __forceinline__ float htanh(float x){
  return __builtin_amdgcn_fmed3f(x, -1.f, 1.f);
}
__device__ __forceinline__ bfx8 frag_f32(const float* p0, const float* p1){
  fx4 lo = *(const fx4*)p0, hi = *(const fx4*)p1;
  bfx8 r;
  r[0]=(short)f2bfu(lo[0]); r[1]=(short)f2bfu(lo[1]); r[2]=(short)f2bfu(lo[2]); r[3]=(short)f2bfu(lo[3]);
  r[4]=(short)f2bfu(hi[0]); r[5]=(short)f2bfu(hi[1]); r[6]=(short)f2bfu(hi[2]); r[7]=(short)f2bfu(hi[3]);
  return r;
}
__device__ __forceinline__ bfx8 frag_lds(const unsigned short* p0, const unsigned short* p1){
  sx4 lo = *(const sx4*)p0, hi = *(const sx4*)p1;
  bfx8 r;
  r[0]=lo[0]; r[1]=lo[1]; r[2]=lo[2]; r[3]=lo[3];
  r[4]=hi[0]; r[5]=hi[1]; r[6]=hi[2]; r[7]=hi[3];
  return r;
}
__device__ __forceinline__ bfx8 cat(ix2 lo, ix2 hi){
  ix4 t; t[0]=lo[0]; t[1]=lo[1]; t[2]=hi[0]; t[3]=hi[1];
  return __builtin_bit_cast(bfx8, t);
}

#define MFMA(A,B,C) __builtin_amdgcn_mfma_f32_16x16x32_bf16((A),(B),(C),0,0,0)

// One self-sufficient wave per 16 cells (4k x 4n). Zero barriers.
// Gates transposed (A = weight rows, B = h cells): D[row = j-part 4g+r][col = cell cc].
// h round-trips through PER-WAVE LDS using the R3-verified [cell*72 + d] addressing.
__global__ __launch_bounds__(256, 2)
void gcrl_fused(const float* __restrict__ obs, const float* __restrict__ pred,
                const float* __restrict__ w1, const float* __restrict__ b1,
                const float* __restrict__ w2, const float* __restrict__ b2,
                const float* __restrict__ wih, const float* __restrict__ whh,
                const float* __restrict__ bih, const float* __restrict__ bhh,
                const float* __restrict__ posw, const float* __restrict__ posb,
                float* __restrict__ out)
{
  __shared__ unsigned short hbuf[4][2][1152];  // [wave][buf][cell*72 + d]
  __shared__ unsigned short l1w[4][16][36];    // [wave][cell][mid 32 + pad]
  __shared__ float xsw[4][19][4][2];           // [wave][row][nloc][comp]

  const int tid = threadIdx.x;
  const int w   = tid >> 6;
  const int l   = tid & 63;
  const int g   = l >> 4;
  const int cc  = l & 15;

  const int bid = blockIdx.x;
  const int k0  = (bid % 5) * 4;
  const int n0b = (bid / 5) * 16;

  const int kc   = k0 + (cc >> 2);
  const int nc   = n0b + w * 4 + (cc & 3);
  const int nloc = cc & 3;

  // ---- per-wave obs staging (19 rows x 4 n x 2) -- no barrier needed ----
  for (int i = l; i < 152; i += 64){
    const int row = i >> 3, rem = i & 7;
    xsw[w][row][rem >> 1][rem & 1] =
      obs[(size_t)row * (NW * 2) + (size_t)(n0b + w * 4 + (rem >> 1)) * 2 + (rem & 1)];
  }

  // ---- weights in registers: full W_hh (16 row-tiles x 2 chunks), from f32 ----
  bfx8 wf[16][2];
  bfx8 xa[16];   // x+bias A-frags: elems 0,1 = wx0,wx1; elem 2 = bsum (g==0 lanes)
  #pragma unroll
  for (int ty = 0; ty < 4; ++ty){
    #pragma unroll
    for (int rt = 0; rt < 4; ++rt){
      const int j = ty * 64 + rt * 16 + cc;
      #pragma unroll
      for (int kt = 0; kt < 2; ++kt)
        wf[ty*4+rt][kt] = frag_f32(&whh[j*64 + kt*32 + 4*g],
                                   &whh[j*64 + kt*32 + 16 + 4*g]);
      const unsigned xw = cvtpk(wih[2*j], wih[2*j+1]);
      const unsigned bw = f2bfu(bih[j] + bhh[j]);
      ix4 t4;
      t4[0] = (g == 0) ? (int)xw : 0;
      t4[1] = (g == 0) ? (int)bw : 0;
      t4[2] = 0; t4[3] = 0;
      xa[ty*4+rt] = __builtin_bit_cast(bfx8, t4);
    }
  }
  bfx8 pf[2];
  {
    const int c2 = (cc < 2) ? cc : 0;
    #pragma unroll
    for (int kt = 0; kt < 2; ++kt)
      pf[kt] = frag_f32(&posw[c2*64 + kt*32 + 4*g], &posw[c2*64 + kt*32 + 16 + 4*g]);
  }
  const fx4 pC = {posb[0], posb[1], 0.f, 0.f};

  // ---- h0 MLP stage 1 (R3-verified pattern, per-wave) ----
  {
    const float* Pr = pred + ((size_t)kc * NW + nc) * 64;
    bfx8 pa0 = frag_f32(&Pr[4*g],      &Pr[16 + 4*g]);
    bfx8 pa1 = frag_f32(&Pr[32 + 4*g], &Pr[48 + 4*g]);
    #pragma unroll
    for (int nt = 0; nt < 2; ++nt){
      const int j1 = nt * 16 + cc;
      bfx8 bf0 = frag_f32(&w1[j1*64 + 4*g],      &w1[j1*64 + 16 + 4*g]);
      bfx8 bf1 = frag_f32(&w1[j1*64 + 32 + 4*g], &w1[j1*64 + 48 + 4*g]);
      const float bb = b1[j1];
      fx4 acc = {bb, bb, bb, bb};
      acc = MFMA(pa0, bf0, acc);
      acc = MFMA(pa1, bf1, acc);
      #pragma unroll
      for (int r = 0; r < 4; ++r){
        const float xv = acc[r];
        l1w[w][g*4 + r][nt*16 + cc] =
          (unsigned short)f2bfu(fmaxf(xv, 0.f) + 0.01f * fminf(xv, 0.f));
      }
    }
  }
  // ---- h0 MLP stage 2 (R3-verified): A = W2 rows, B = l1 cells -> h into LDS ----
  {
    bfx8 bfr = frag_lds(&l1w[w][cc][4*g], &l1w[w][cc][16 + 4*g]);
    #pragma unroll
    for (int rt = 0; rt < 4; ++rt){
      bfx8 afr = frag_f32(&w2[(rt*16 + cc)*32 + 4*g], &w2[(rt*16 + cc)*32 + 16 + 4*g]);
      fx4 ci = *(const fx4*)&b2[rt*16 + 4*g];
      fx4 acc = MFMA(afr, bfr, ci);
      ix2 pk;
      pk[0] = (int)cvtpk(acc[0], acc[1]);
      pk[1] = (int)cvtpk(acc[2], acc[3]);
      *(ix2*)&hbuf[w][0][cc*72 + rt*16 + 4*g] = pk;
    }
  }

  float cst[4][4];
  #pragma unroll
  for (int a_ = 0; a_ < 4; ++a_)
    #pragma unroll
    for (int b_ = 0; b_ < 4; ++b_) cst[a_][b_] = 0.f;

  const unsigned short* const rb0 = &hbuf[w][0][cc*72 + 4*g];
  const unsigned short* const rb1 = &hbuf[w][1][cc*72 + 4*g];
  unsigned short* const wb0 = &hbuf[w][0][cc*72 + 4*g];
  unsigned short* const wb1 = &hbuf[w][1][cc*72 + 4*g];

  float* const outp = out + ((size_t)kc * NW + nc) * 2;
  const unsigned one_bf = (g == 0) ? 0x00003F80u : 0u;

#define STEP(XI, TPREV, DOPROJ, RB, WB) do{                                    \
    const fx2 xL = *(const fx2*)&xsw[w][(XI)][nloc][0];                        \
    const unsigned xw_ = cvtpk(xL[0], xL[1]);                                  \
    ix4 xb4; xb4[0] = (g==0) ? (int)xw_ : 0; xb4[1] = (int)one_bf;             \
    xb4[2] = 0; xb4[3] = 0;                                                    \
    const bfx8 xbf = __builtin_bit_cast(bfx8, xb4);                            \
    ix2 lA0 = *(const ix2*)(RB);        ix2 hA0 = *(const ix2*)((RB) + 16);    \
    ix2 lA1 = *(const ix2*)((RB) + 32); ix2 hA1 = *(const ix2*)((RB) + 48);    \
    bfx8 hb0 = cat(lA0, hA0), hb1 = cat(lA1, hA1);                             \
    if (DOPROJ){                                                               \
      fx4 oa = MFMA(pf[0], hb0, pC);                                           \
      oa = MFMA(pf[1], hb1, oa);                                               \
      if (g == 0){                                                             \
        fx2 ov; ov[0] = oa[0]; ov[1] = oa[1];                                  \
        *(fx2*)(outp + (size_t)(TPREV) * (KK * NW * 2)) = ov;                  \
      }                                                                        \
    }                                                                          \
    _Pragma("unroll")                                                          \
    for (int rt = 0; rt < 4; ++rt){                                            \
      const fx4 z = {0.f, 0.f, 0.f, 0.f};                                      \
      fx4 ai = MFMA(xa[0*4+rt], xbf, z);                                       \
      ai = MFMA(wf[0*4+rt][0], hb0, ai); ai = MFMA(wf[0*4+rt][1], hb1, ai);    \
      fx4 af = MFMA(xa[1*4+rt], xbf, z);                                       \
      af = MFMA(wf[1*4+rt][0], hb0, af); af = MFMA(wf[1*4+rt][1], hb1, af);    \
      fx4 ag2 = MFMA(xa[2*4+rt], xbf, z);                                      \
      ag2 = MFMA(wf[2*4+rt][0], hb0, ag2); ag2 = MFMA(wf[2*4+rt][1], hb1, ag2);\
      fx4 ao = MFMA(xa[3*4+rt], xbf, z);                                       \
      ao = MFMA(wf[3*4+rt][0], hb0, ao); ao = MFMA(wf[3*4+rt][1], hb1, ao);    \
      float hq[4];                                                             \
      _Pragma("unroll")                                                        \
      for (int r = 0; r < 4; ++r){                                             \
        const float cn = fmaf(hsig(af[r]), cst[rt][r], hsig(ai[r])*htanh(ag2[r])); \
        cst[rt][r] = cn;                                                       \
        hq[r] = hsig(ao[r]) * htanh(cn);                                       \
      }                                                                        \
      ix2 pk;                                                                  \
      pk[0] = (int)cvtpk(hq[0], hq[1]);                                        \
      pk[1] = (int)cvtpk(hq[2], hq[3]);                                        \
      *(ix2*)((WB) + rt*16) = pk;                                              \
    }                                                                          \
  }while(0)

  for (int t = 0; t < T_STEPS; t += 2){
    STEP((t == 0 ? 0 : t - 1), t - 1, (t > 0), rb0, wb1);   // read buf0 -> write buf1
    STEP(t,                    t,     1,       rb1, wb0);   // read buf1 -> write buf0
  }

  // ---- epilogue: out[19] from h_20 (buf 0) ----
  {
    ix2 l0 = *(const ix2*)rb0,        h0 = *(const ix2*)(rb0 + 16);
    ix2 l1 = *(const ix2*)(rb0 + 32), h1 = *(const ix2*)(rb0 + 48);
    bfx8 hb0 = cat(l0, h0), hb1 = cat(l1, h1);
    fx4 oa = MFMA(pf[0], hb0, pC);
    oa = MFMA(pf[1], hb1, oa);
    if (g == 0){
      fx2 ov; ov[0] = oa[0]; ov[1] = oa[1];
      *(fx2*)(outp + (size_t)19 * (KK * NW * 2)) = ov;
    }
  }
#undef STEP
}

extern "C" void kernel_launch(void* const* d_in, const int* in_sizes, int n_in,
                              void* d_out, int out_size, void* d_ws, size_t ws_size,
                              hipStream_t stream){
  const float* obs  = (const float*)d_in[0];
  const float* pred = (const float*)d_in[1];
  const float* w1   = (const float*)d_in[2];
  const float* b1   = (const float*)d_in[3];
  const float* w2   = (const float*)d_in[4];
  const float* b2   = (const float*)d_in[5];
  const float* wih  = (const float*)d_in[6];
  const float* whh  = (const float*)d_in[7];
  const float* bih  = (const float*)d_in[8];
  const float* bhh  = (const float*)d_in[9];
  const float* posw = (const float*)d_in[10];
  const float* posb = (const float*)d_in[11];
  float* o = (float*)d_out;

  dim3 grid(5 * (NW / 16));   // 15625 blocks x 4 waves x 16 cells
  dim3 block(256);
  gcrl_fused<<<grid, block, 0, stream>>>(obs, pred, w1, b1, w2, b2,
                                         wih, whh, bih, bhh, posw, posb, o);
}

// Round 9
// 1936.420 us; speedup vs baseline: 1.0996x; 1.0996x over previous
//
#include <hip/hip_runtime.h>

#define T_STEPS 20
#define KK      20
#define NW      50000

typedef __attribute__((ext_vector_type(8))) short bfx8;
typedef __attribute__((ext_vector_type(4))) short sx4;
typedef __attribute__((ext_vector_type(4))) float fx4;
typedef __attribute__((ext_vector_type(2))) float fx2;
typedef __attribute__((ext_vector_type(4))) int   ix4;
typedef __attribute__((ext_vector_type(2))) int   ix2;

__device__ __forceinline__ unsigned f2bfu(float f){
  unsigned u = __builtin_bit_cast(unsigned, f);
  return ((u + 0x7FFFu + ((u >> 16) & 1u)) >> 16);
}
__device__ __forceinline__ unsigned cvtpk(float lo, float hi){
  unsigned r; asm("v_cvt_pk_bf16_f32 %0, %1, %2" : "=v"(r) : "v"(lo), "v"(hi)); return r;
}
__device__ __forceinline__ float hsig(float x){
  return __builtin_amdgcn_fmed3f(fmaf(x, 0.16666667f, 0.5f), 0.f, 1.f);
}
__device__ __forceinline__ float htanh(float x){
  return __builtin_amdgcn_fmed3f(x, -1.f, 1.f);
}
__device__ __forceinline__ bfx8 frag_lds(const unsigned short* p0, const unsigned short* p1){
  sx4 lo = *(const sx4*)p0, hi = *(const sx4*)p1;
  bfx8 r;
  r[0]=lo[0]; r[1]=lo[1]; r[2]=lo[2]; r[3]=lo[3];
  r[4]=hi[0]; r[5]=hi[1]; r[6]=hi[2]; r[7]=hi[3];
  return r;
}
__device__ __forceinline__ bfx8 frag_f32(const float* p0, const float* p1){
  fx4 lo = *(const fx4*)p0, hi = *(const fx4*)p1;
  bfx8 r;
  r[0]=(short)f2bfu(lo[0]); r[1]=(short)f2bfu(lo[1]); r[2]=(short)f2bfu(lo[2]); r[3]=(short)f2bfu(lo[3]);
  r[4]=(short)f2bfu(hi[0]); r[5]=(short)f2bfu(hi[1]); r[6]=(short)f2bfu(hi[2]); r[7]=(short)f2bfu(hi[3]);
  return r;
}
__device__ __forceinline__ bfx8 cat(ix2 lo, ix2 hi){
  ix4 t; t[0]=lo[0]; t[1]=lo[1]; t[2]=hi[0]; t[3]=hi[1];
  return __builtin_bit_cast(bfx8, t);
}

#define MFMA(A,B,C) __builtin_amdgcn_mfma_f32_16x16x32_bf16((A),(B),(C),0,0,0)

// R5-verbatim structure (verified passing). ONLY change: projection outputs are
// staged in LDS (obuf) and flushed once per block as full 128B lines, killing
// the 10x write amplification R5's 32B partial-line global stores caused.
__global__ __launch_bounds__(256, 2)
void gcrl_fused(const float* __restrict__ obs, const float* __restrict__ pred,
                const float* __restrict__ w1, const float* __restrict__ b1,
                const float* __restrict__ w2, const float* __restrict__ b2,
                const float* __restrict__ wih, const float* __restrict__ whh,
                const float* __restrict__ bih, const float* __restrict__ bhh,
                const float* __restrict__ posw, const float* __restrict__ posb,
                float* __restrict__ out)
{
  __shared__ unsigned short hbuf[4][2][1152];  // [wave][buf][cell*72 + d]
  __shared__ unsigned short l1w[4][16][36];    // [wave][cell][mid 32 + pad]
  __shared__ float          xsw[4][19][4][2];  // [wave][row][nloc][comp]
  __shared__ float          obuf[20][4][34];   // [t][k-part][2*(4w+nn)] (+pad)

  const int tid = threadIdx.x;
  const int w   = tid >> 6;
  const int l   = tid & 63;
  const int g   = l >> 4;
  const int cc  = l & 15;

  const int bid = blockIdx.x;
  const int k0  = (bid % 5) * 4;
  const int n0b = (bid / 5) * 16;

  const int kc   = k0 + (cc >> 2);
  const int nc   = n0b + w * 4 + (cc & 3);
  const int nloc = cc & 3;

  // ---- per-wave obs staging (R5-verbatim) ----
  for (int i = l; i < 152; i += 64){
    const int row = i >> 3, rem = i & 7;
    xsw[w][row][rem >> 1][rem & 1] =
      obs[(size_t)row * (NW * 2) + (size_t)(n0b + w * 4 + (rem >> 1)) * 2 + (rem & 1)];
  }

  // ---- weights in registers (R5-verbatim) ----
  bfx8 wf[16][2];
  bfx8 xa[16];
  #pragma unroll
  for (int ty = 0; ty < 4; ++ty){
    #pragma unroll
    for (int rt = 0; rt < 4; ++rt){
      const int j = ty * 64 + rt * 16 + cc;
      #pragma unroll
      for (int kt = 0; kt < 2; ++kt)
        wf[ty*4+rt][kt] = frag_f32(&whh[j*64 + kt*32 + 4*g],
                                   &whh[j*64 + kt*32 + 16 + 4*g]);
      const unsigned xw = cvtpk(wih[2*j], wih[2*j+1]);
      const unsigned bw = f2bfu(bih[j] + bhh[j]);
      ix4 t4;
      t4[0] = (g == 0) ? (int)xw : 0;
      t4[1] = (g == 0) ? (int)bw : 0;
      t4[2] = 0; t4[3] = 0;
      xa[ty*4+rt] = __builtin_bit_cast(bfx8, t4);
    }
  }
  bfx8 pf[2];
  {
    const int c2 = (cc < 2) ? cc : 0;
    pf[0] = frag_f32(&posw[c2*64 + 4*g],      &posw[c2*64 + 16 + 4*g]);
    pf[1] = frag_f32(&posw[c2*64 + 32 + 4*g], &posw[c2*64 + 48 + 4*g]);
  }
  const fx4 pC = {posb[0], posb[1], 0.f, 0.f};

  // ---- h0 MLP stage 1 (R5-verbatim) ----
  {
    const float* Pr = pred + ((size_t)kc * NW + nc) * 64;
    bfx8 pa0 = frag_f32(&Pr[4*g],      &Pr[16 + 4*g]);
    bfx8 pa1 = frag_f32(&Pr[32 + 4*g], &Pr[48 + 4*g]);
    #pragma unroll
    for (int nt = 0; nt < 2; ++nt){
      const int j1 = nt * 16 + cc;
      bfx8 bf0 = frag_f32(&w1[j1*64 + 4*g],      &w1[j1*64 + 16 + 4*g]);
      bfx8 bf1 = frag_f32(&w1[j1*64 + 32 + 4*g], &w1[j1*64 + 48 + 4*g]);
      const float bb = b1[j1];
      fx4 acc = {bb, bb, bb, bb};
      acc = MFMA(pa0, bf0, acc);
      acc = MFMA(pa1, bf1, acc);
      #pragma unroll
      for (int r = 0; r < 4; ++r){
        const float xv = acc[r];
        l1w[w][g*4 + r][nt*16 + cc] =
          (unsigned short)f2bfu(fmaxf(xv, 0.f) + 0.01f * fminf(xv, 0.f));
      }
    }
  }
  // ---- h0 MLP stage 2 (R5-verbatim) ----
  {
    bfx8 bfr = frag_lds(&l1w[w][cc][4*g], &l1w[w][cc][16 + 4*g]);
    #pragma unroll
    for (int rt = 0; rt < 4; ++rt){
      bfx8 afr = frag_f32(&w2[(rt*16 + cc)*32 + 4*g], &w2[(rt*16 + cc)*32 + 16 + 4*g]);
      fx4 ci = *(const fx4*)&b2[rt*16 + 4*g];
      fx4 acc = MFMA(afr, bfr, ci);
      ix2 pk;
      pk[0] = (int)cvtpk(acc[0], acc[1]);
      pk[1] = (int)cvtpk(acc[2], acc[3]);
      *(ix2*)&hbuf[w][0][cc*72 + rt*16 + 4*g] = pk;
    }
  }

  float cst[4][4];
  #pragma unroll
  for (int a_ = 0; a_ < 4; ++a_)
    #pragma unroll
    for (int b_ = 0; b_ < 4; ++b_) cst[a_][b_] = 0.f;

  const unsigned short* const rb0 = &hbuf[w][0][cc*72 + 4*g];
  const unsigned short* const rb1 = &hbuf[w][1][cc*72 + 4*g];
  unsigned short* const wb0 = &hbuf[w][0][cc*72 + 4*g];
  unsigned short* const wb1 = &hbuf[w][1][cc*72 + 4*g];

  const unsigned one_bf = (g == 0) ? 0x00003F80u : 0u;
  const int okk = cc >> 2;              // k-part of this lane's cell
  const int onn = (w * 4 + (cc & 3)) * 2;

#define STEP(XI, TPREV, DOPROJ, RB, WB) do{                                    \
    const fx2 xL = *(const fx2*)&xsw[w][(XI)][nloc][0];                        \
    const unsigned xw_ = cvtpk(xL[0], xL[1]);                                  \
    ix4 xb4; xb4[0] = (g==0) ? (int)xw_ : 0; xb4[1] = (int)one_bf;             \
    xb4[2] = 0; xb4[3] = 0;                                                    \
    const bfx8 xbf = __builtin_bit_cast(bfx8, xb4);                            \
    ix2 lA0 = *(const ix2*)(RB);        ix2 hA0 = *(const ix2*)((RB) + 16);    \
    ix2 lA1 = *(const ix2*)((RB) + 32); ix2 hA1 = *(const ix2*)((RB) + 48);    \
    bfx8 hb0 = cat(lA0, hA0), hb1 = cat(lA1, hA1);                             \
    if (DOPROJ){                                                               \
      fx4 oa = MFMA(pf[0], hb0, pC);                                           \
      oa = MFMA(pf[1], hb1, oa);                                               \
      if (g == 0){                                                             \
        fx2 ov; ov[0] = oa[0]; ov[1] = oa[1];                                  \
        *(fx2*)&obuf[(TPREV)][okk][onn] = ov;                                  \
      }                                                                        \
    }                                                                          \
    _Pragma("unroll")                                                          \
    for (int rt = 0; rt < 4; ++rt){                                            \
      const fx4 z = {0.f, 0.f, 0.f, 0.f};                                      \
      fx4 ai = MFMA(xa[0*4+rt], xbf, z);                                       \
      ai = MFMA(wf[0*4+rt][0], hb0, ai); ai = MFMA(wf[0*4+rt][1], hb1, ai);    \
      fx4 af = MFMA(xa[1*4+rt], xbf, z);                                       \
      af = MFMA(wf[1*4+rt][0], hb0, af); af = MFMA(wf[1*4+rt][1], hb1, af);    \
      fx4 ag2 = MFMA(xa[2*4+rt], xbf, z);                                      \
      ag2 = MFMA(wf[2*4+rt][0], hb0, ag2); ag2 = MFMA(wf[2*4+rt][1], hb1, ag2);\
      fx4 ao = MFMA(xa[3*4+rt], xbf, z);                                       \
      ao = MFMA(wf[3*4+rt][0], hb0, ao); ao = MFMA(wf[3*4+rt][1], hb1, ao);    \
      float hq[4];                                                             \
      _Pragma("unroll")                                                        \
      for (int r = 0; r < 4; ++r){                                             \
        const float cn = fmaf(hsig(af[r]), cst[rt][r], hsig(ai[r])*htanh(ag2[r])); \
        cst[rt][r] = cn;                                                       \
        hq[r] = hsig(ao[r]) * htanh(cn);                                       \
      }                                                                        \
      ix2 pk;                                                                  \
      pk[0] = (int)cvtpk(hq[0], hq[1]);                                        \
      pk[1] = (int)cvtpk(hq[2], hq[3]);                                        \
      *(ix2*)((WB) + rt*16) = pk;                                              \
    }                                                                          \
  }while(0)

  for (int t = 0; t < T_STEPS; t += 2){
    STEP((t == 0 ? 0 : t - 1), t - 1, (t > 0), rb0, wb1);   // buf0 -> buf1
    STEP(t,                    t,     1,       rb1, wb0);   // buf1 -> buf0
  }

  // ---- epilogue: out[19] from h_20 (buf 0) ----
  {
    ix2 l0 = *(const ix2*)rb0,        h0 = *(const ix2*)(rb0 + 16);
    ix2 l1 = *(const ix2*)(rb0 + 32), h1 = *(const ix2*)(rb0 + 48);
    bfx8 hb0 = cat(l0, h0), hb1 = cat(l1, h1);
    fx4 oa = MFMA(pf[0], hb0, pC);
    oa = MFMA(pf[1], hb1, oa);
    if (g == 0){
      fx2 ov; ov[0] = oa[0]; ov[1] = oa[1];
      *(fx2*)&obuf[19][okk][onn] = ov;
    }
  }
#undef STEP

  // ---- coalesced flush: 80 full 128B lines per block ----
  __syncthreads();
  {
    const int lane32 = tid & 31;
    for (int p = tid >> 5; p < 80; p += 8){
      const int t  = p >> 2;
      const int kk = p & 3;
      out[(size_t)t * (KK * NW * 2) + (size_t)(k0 + kk) * (NW * 2)
          + (size_t)n0b * 2 + lane32] = obuf[t][kk][lane32];
    }
  }
}

extern "C" void kernel_launch(void* const* d_in, const int* in_sizes, int n_in,
                              void* d_out, int out_size, void* d_ws, size_t ws_size,
                              hipStream_t stream){
  const float* obs  = (const float*)d_in[0];
  const float* pred = (const float*)d_in[1];
  const float* w1   = (const float*)d_in[2];
  const float* b1   = (const float*)d_in[3];
  const float* w2   = (const float*)d_in[4];
  const float* b2   = (const float*)d_in[5];
  const float* wih  = (const float*)d_in[6];
  const float* whh  = (const float*)d_in[7];
  const float* bih  = (const float*)d_in[8];
  const float* bhh  = (const float*)d_in[9];
  const float* posw = (const float*)d_in[10];
  const float* posb = (const float*)d_in[11];
  float* o = (float*)d_out;

  dim3 grid(5 * (NW / 16));   // 15625 blocks: k by (cc>>2), n by wave*4 + (cc&3)
  dim3 block(256);
  gcrl_fused<<<grid, block, 0, stream>>>(obs, pred, w1, b1, w2, b2,
                                         wih, whh, bih, bhh, posw, posb, o);
}

// Round 10
// 1723.259 us; speedup vs baseline: 1.2356x; 1.1237x over previous
//
#include <hip/hip_runtime.h>

#define T_STEPS 20
#define KK      20
#define NW      50000

typedef __attribute__((ext_vector_type(8))) short bfx8;
typedef __attribute__((ext_vector_type(4))) short sx4;
typedef __attribute__((ext_vector_type(4))) float fx4;
typedef __attribute__((ext_vector_type(2))) float fx2;
typedef __attribute__((ext_vector_type(4))) int   ix4;
typedef __attribute__((ext_vector_type(2))) int   ix2;

__device__ __forceinline__ unsigned f2bfu(float f){
  unsigned u = __builtin_bit_cast(unsigned, f);
  return ((u + 0x7FFFu + ((u >> 16) & 1u)) >> 16);
}
__device__ __forceinline__ unsigned cvtpk(float lo, float hi){
  unsigned r; asm("v_cvt_pk_bf16_f32 %0, %1, %2" : "=v"(r) : "v"(lo), "v"(hi)); return r;
}
__device__ __forceinline__ float hsig(float x){
  return __builtin_amdgcn_fmed3f(fmaf(x, 0.16666667f, 0.5f), 0.f, 1.f);
}
__device__ __forceinline__ float htanh(float x){
  return __builtin_amdgcn_fmed3f(x, -1.f, 1.f);
}
__device__ __forceinline__ bfx8 frag_lds(const unsigned short* p0, const unsigned short* p1){
  sx4 lo = *(const sx4*)p0, hi = *(const sx4*)p1;
  bfx8 r;
  r[0]=lo[0]; r[1]=lo[1]; r[2]=lo[2]; r[3]=lo[3];
  r[4]=hi[0]; r[5]=hi[1]; r[6]=hi[2]; r[7]=hi[3];
  return r;
}
__device__ __forceinline__ bfx8 frag_f32(const float* p0, const float* p1){
  fx4 lo = *(const fx4*)p0, hi = *(const fx4*)p1;
  bfx8 r;
  r[0]=(short)f2bfu(lo[0]); r[1]=(short)f2bfu(lo[1]); r[2]=(short)f2bfu(lo[2]); r[3]=(short)f2bfu(lo[3]);
  r[4]=(short)f2bfu(hi[0]); r[5]=(short)f2bfu(hi[1]); r[6]=(short)f2bfu(hi[2]); r[7]=(short)f2bfu(hi[3]);
  return r;
}
__device__ __forceinline__ bfx8 cat(ix2 lo, ix2 hi){
  ix4 t; t[0]=lo[0]; t[1]=lo[1]; t[2]=hi[0]; t[3]=hi[1];
  return __builtin_bit_cast(bfx8, t);
}

#define MFMA(A,B,C) __builtin_amdgcn_mfma_f32_16x16x32_bf16((A),(B),(C),0,0,0)

// R9-verbatim (verified passing). ONLY change: occupancy bound (256,1) +
// waves_per_eu(1,1) so the allocator gets the ~280 VGPRs this structure needs
// instead of capping at 128 and spilling wf/xa to scratch (R5/R9: 1.8 GB of
// scratch HBM traffic, latency-bound at 5-23% busy).
__global__ __launch_bounds__(256, 1) __attribute__((amdgpu_waves_per_eu(1, 1)))
void gcrl_fused(const float* __restrict__ obs, const float* __restrict__ pred,
                const float* __restrict__ w1, const float* __restrict__ b1,
                const float* __restrict__ w2, const float* __restrict__ b2,
                const float* __restrict__ wih, const float* __restrict__ whh,
                const float* __restrict__ bih, const float* __restrict__ bhh,
                const float* __restrict__ posw, const float* __restrict__ posb,
                float* __restrict__ out)
{
  __shared__ unsigned short hbuf[4][2][1152];  // [wave][buf][cell*72 + d]
  __shared__ unsigned short l1w[4][16][36];    // [wave][cell][mid 32 + pad]
  __shared__ float          xsw[4][19][4][2];  // [wave][row][nloc][comp]
  __shared__ float          obuf[20][4][34];   // [t][k-part][2*(4w+nn)] (+pad)

  const int tid = threadIdx.x;
  const int w   = tid >> 6;
  const int l   = tid & 63;
  const int g   = l >> 4;
  const int cc  = l & 15;

  const int bid = blockIdx.x;
  const int k0  = (bid % 5) * 4;
  const int n0b = (bid / 5) * 16;

  const int kc   = k0 + (cc >> 2);
  const int nc   = n0b + w * 4 + (cc & 3);
  const int nloc = cc & 3;

  // ---- per-wave obs staging (R5-verbatim) ----
  for (int i = l; i < 152; i += 64){
    const int row = i >> 3, rem = i & 7;
    xsw[w][row][rem >> 1][rem & 1] =
      obs[(size_t)row * (NW * 2) + (size_t)(n0b + w * 4 + (rem >> 1)) * 2 + (rem & 1)];
  }

  // ---- weights in registers (R5-verbatim) ----
  bfx8 wf[16][2];
  bfx8 xa[16];
  #pragma unroll
  for (int ty = 0; ty < 4; ++ty){
    #pragma unroll
    for (int rt = 0; rt < 4; ++rt){
      const int j = ty * 64 + rt * 16 + cc;
      #pragma unroll
      for (int kt = 0; kt < 2; ++kt)
        wf[ty*4+rt][kt] = frag_f32(&whh[j*64 + kt*32 + 4*g],
                                   &whh[j*64 + kt*32 + 16 + 4*g]);
      const unsigned xw = cvtpk(wih[2*j], wih[2*j+1]);
      const unsigned bw = f2bfu(bih[j] + bhh[j]);
      ix4 t4;
      t4[0] = (g == 0) ? (int)xw : 0;
      t4[1] = (g == 0) ? (int)bw : 0;
      t4[2] = 0; t4[3] = 0;
      xa[ty*4+rt] = __builtin_bit_cast(bfx8, t4);
    }
  }
  bfx8 pf[2];
  {
    const int c2 = (cc < 2) ? cc : 0;
    pf[0] = frag_f32(&posw[c2*64 + 4*g],      &posw[c2*64 + 16 + 4*g]);
    pf[1] = frag_f32(&posw[c2*64 + 32 + 4*g], &posw[c2*64 + 48 + 4*g]);
  }
  const fx4 pC = {posb[0], posb[1], 0.f, 0.f};

  // ---- h0 MLP stage 1 (R5-verbatim) ----
  {
    const float* Pr = pred + ((size_t)kc * NW + nc) * 64;
    bfx8 pa0 = frag_f32(&Pr[4*g],      &Pr[16 + 4*g]);
    bfx8 pa1 = frag_f32(&Pr[32 + 4*g], &Pr[48 + 4*g]);
    #pragma unroll
    for (int nt = 0; nt < 2; ++nt){
      const int j1 = nt * 16 + cc;
      bfx8 bf0 = frag_f32(&w1[j1*64 + 4*g],      &w1[j1*64 + 16 + 4*g]);
      bfx8 bf1 = frag_f32(&w1[j1*64 + 32 + 4*g], &w1[j1*64 + 48 + 4*g]);
      const float bb = b1[j1];
      fx4 acc = {bb, bb, bb, bb};
      acc = MFMA(pa0, bf0, acc);
      acc = MFMA(pa1, bf1, acc);
      #pragma unroll
      for (int r = 0; r < 4; ++r){
        const float xv = acc[r];
        l1w[w][g*4 + r][nt*16 + cc] =
          (unsigned short)f2bfu(fmaxf(xv, 0.f) + 0.01f * fminf(xv, 0.f));
      }
    }
  }
  // ---- h0 MLP stage 2 (R5-verbatim) ----
  {
    bfx8 bfr = frag_lds(&l1w[w][cc][4*g], &l1w[w][cc][16 + 4*g]);
    #pragma unroll
    for (int rt = 0; rt < 4; ++rt){
      bfx8 afr = frag_f32(&w2[(rt*16 + cc)*32 + 4*g], &w2[(rt*16 + cc)*32 + 16 + 4*g]);
      fx4 ci = *(const fx4*)&b2[rt*16 + 4*g];
      fx4 acc = MFMA(afr, bfr, ci);
      ix2 pk;
      pk[0] = (int)cvtpk(acc[0], acc[1]);
      pk[1] = (int)cvtpk(acc[2], acc[3]);
      *(ix2*)&hbuf[w][0][cc*72 + rt*16 + 4*g] = pk;
    }
  }

  float cst[4][4];
  #pragma unroll
  for (int a_ = 0; a_ < 4; ++a_)
    #pragma unroll
    for (int b_ = 0; b_ < 4; ++b_) cst[a_][b_] = 0.f;

  const unsigned short* const rb0 = &hbuf[w][0][cc*72 + 4*g];
  const unsigned short* const rb1 = &hbuf[w][1][cc*72 + 4*g];
  unsigned short* const wb0 = &hbuf[w][0][cc*72 + 4*g];
  unsigned short* const wb1 = &hbuf[w][1][cc*72 + 4*g];

  const unsigned one_bf = (g == 0) ? 0x00003F80u : 0u;
  const int okk = cc >> 2;              // k-part of this lane's cell
  const int onn = (w * 4 + (cc & 3)) * 2;

#define STEP(XI, TPREV, DOPROJ, RB, WB) do{                                    \
    const fx2 xL = *(const fx2*)&xsw[w][(XI)][nloc][0];                        \
    const unsigned xw_ = cvtpk(xL[0], xL[1]);                                  \
    ix4 xb4; xb4[0] = (g==0) ? (int)xw_ : 0; xb4[1] = (int)one_bf;             \
    xb4[2] = 0; xb4[3] = 0;                                                    \
    const bfx8 xbf = __builtin_bit_cast(bfx8, xb4);                            \
    ix2 lA0 = *(const ix2*)(RB);        ix2 hA0 = *(const ix2*)((RB) + 16);    \
    ix2 lA1 = *(const ix2*)((RB) + 32); ix2 hA1 = *(const ix2*)((RB) + 48);    \
    bfx8 hb0 = cat(lA0, hA0), hb1 = cat(lA1, hA1);                             \
    if (DOPROJ){                                                               \
      fx4 oa = MFMA(pf[0], hb0, pC);                                           \
      oa = MFMA(pf[1], hb1, oa);                                               \
      if (g == 0){                                                             \
        fx2 ov; ov[0] = oa[0]; ov[1] = oa[1];                                  \
        *(fx2*)&obuf[(TPREV)][okk][onn] = ov;                                  \
      }                                                                        \
    }                                                                          \
    _Pragma("unroll")                                                          \
    for (int rt = 0; rt < 4; ++rt){                                            \
      const fx4 z = {0.f, 0.f, 0.f, 0.f};                                      \
      fx4 ai = MFMA(xa[0*4+rt], xbf, z);                                       \
      ai = MFMA(wf[0*4+rt][0], hb0, ai); ai = MFMA(wf[0*4+rt][1], hb1, ai);    \
      fx4 af = MFMA(xa[1*4+rt], xbf, z);                                       \
      af = MFMA(wf[1*4+rt][0], hb0, af); af = MFMA(wf[1*4+rt][1], hb1, af);    \
      fx4 ag2 = MFMA(xa[2*4+rt], xbf, z);                                      \
      ag2 = MFMA(wf[2*4+rt][0], hb0, ag2); ag2 = MFMA(wf[2*4+rt][1], hb1, ag2);\
      fx4 ao = MFMA(xa[3*4+rt], xbf, z);                                       \
      ao = MFMA(wf[3*4+rt][0], hb0, ao); ao = MFMA(wf[3*4+rt][1], hb1, ao);    \
      float hq[4];                                                             \
      _Pragma("unroll")                                                        \
      for (int r = 0; r < 4; ++r){                                             \
        const float cn = fmaf(hsig(af[r]), cst[rt][r], hsig(ai[r])*htanh(ag2[r])); \
        cst[rt][r] = cn;                                                       \
        hq[r] = hsig(ao[r]) * htanh(cn);                                       \
      }                                                                        \
      ix2 pk;                                                                  \
      pk[0] = (int)cvtpk(hq[0], hq[1]);                                        \
      pk[1] = (int)cvtpk(hq[2], hq[3]);                                        \
      *(ix2*)((WB) + rt*16) = pk;                                              \
    }                                                                          \
  }while(0)

  for (int t = 0; t < T_STEPS; t += 2){
    STEP((t == 0 ? 0 : t - 1), t - 1, (t > 0), rb0, wb1);   // buf0 -> buf1
    STEP(t,                    t,     1,       rb1, wb0);   // buf1 -> buf0
  }

  // ---- epilogue: out[19] from h_20 (buf 0) ----
  {
    ix2 l0 = *(const ix2*)rb0,        h0 = *(const ix2*)(rb0 + 16);
    ix2 l1 = *(const ix2*)(rb0 + 32), h1 = *(const ix2*)(rb0 + 48);
    bfx8 hb0 = cat(l0, h0), hb1 = cat(l1, h1);
    fx4 oa = MFMA(pf[0], hb0, pC);
    oa = MFMA(pf[1], hb1, oa);
    if (g == 0){
      fx2 ov; ov[0] = oa[0]; ov[1] = oa[1];
      *(fx2*)&obuf[19][okk][onn] = ov;
    }
  }
#undef STEP

  // ---- coalesced flush: 80 full 128B lines per block ----
  __syncthreads();
  {
    const int lane32 = tid & 31;
    for (int p = tid >> 5; p < 80; p += 8){
      const int t  = p >> 2;
      const int kk = p & 3;
      out[(size_t)t * (KK * NW * 2) + (size_t)(k0 + kk) * (NW * 2)
          + (size_t)n0b * 2 + lane32] = obuf[t][kk][lane32];
    }
  }
}

extern "C" void kernel_launch(void* const* d_in, const int* in_sizes, int n_in,
                              void* d_out, int out_size, void* d_ws, size_t ws_size,
                              hipStream_t stream){
  const float* obs  = (const float*)d_in[0];
  const float* pred = (const float*)d_in[1];
  const float* w1   = (const float*)d_in[2];
  const float* b1   = (const float*)d_in[3];
  const float* w2   = (const float*)d_in[4];
  const float* b2   = (const float*)d_in[5];
  const float* wih  = (const float*)d_in[6];
  const float* whh  = (const float*)d_in[7];
  const float* bih  = (const float*)d_in[8];
  const float* bhh  = (const float*)d_in[9];
  const float* posw = (const float*)d_in[10];
  const float* posb = (const float*)d_in[11];
  float* o = (float*)d_out;

  dim3 grid(5 * (NW / 16));   // 15625 blocks: k by (cc>>2), n by wave*4 + (cc&3)
  dim3 block(256);
  gcrl_fused<<<grid, block, 0, stream>>>(obs, pred, w1, b1, w2, b2,
                                         wih, whh, bih, bhh, posw, posb, o);
}